// Round 2
// baseline (15858.762 us; speedup 1.0000x reference)
//
#include <hip/hip_runtime.h>
#include <hip/hip_bf16.h>

typedef __hip_bfloat16 bf16;

#define HH 300     // hidden
#define NMOLS 2000
#define AFD 133    // atom feature dim
#define BFD 147    // bond feature dim
// MODE1 K layout: [0,147) f_bonds@W_i | [147,160) zero pad | [160,460) gathered@W_h
#define K1TOT 460
#define G1OFS 160
// MODE2 K layout: [0,133) f_atoms | [133,144) zero pad | [144,444) gathered(a_msg)
#define K2TOT 444
#define G2OFS 144

__device__ inline float bfu(unsigned short s) {
  union { unsigned u; float f; } c; c.u = ((unsigned)s) << 16; return c.f;
}
// load 8 consecutive bf16 from an 8B-aligned pointer, accumulate into s[0..7] with sign
__device__ inline void acc8bf(const bf16* p, float sgn, float* s) {
  const uint2* q = (const uint2*)p;
  uint2 u0 = q[0], u1 = q[1];
  unsigned w[4] = {u0.x, u0.y, u1.x, u1.y};
#pragma unroll
  for (int i = 0; i < 4; i++) {
    union { unsigned u; float f; } lo, hi;
    lo.u = w[i] << 16;
    hi.u = w[i] & 0xffff0000u;
    s[2 * i]     += sgn * lo.f;
    s[2 * i + 1] += sgn * hi.f;
  }
}

// ---------------- Tiled fp32 GEMM with fused gathers ----------------
// BM=128, BN=64, BK=16, 256 threads, 8x4 microtile.
// MODE 0: C = f_bonds @ W_i (K=147);                 msg_out = relu(C), row0=0
// MODE 1: C = f_bonds@W_i + gather(msgc)@W_h (K=460) msg_out = relu(C), row0=0
//         gather row r: sum_j msgc[a2b[b2a[r],j]] - msgc[b2revb[r]]
// MODE 2: C = [f_atoms | sum_j msgc[a2b[r,j]]] @ W_o (K=444); hid = relu(C + bias)
template<int MODE>
__global__ __launch_bounds__(256)
void gemm_k(const float* __restrict__ A0, const float* __restrict__ W0,
            const float* __restrict__ W1, const int* __restrict__ b2a,
            const int* __restrict__ b2revb, const int* __restrict__ a2b,
            const bf16* __restrict__ msgc, const float* __restrict__ bias,
            bf16* __restrict__ msg_out, float* __restrict__ hid_out, int M)
{
  constexpr int K = (MODE == 0) ? BFD : (MODE == 1) ? K1TOT : K2TOT;
  __shared__ __align__(16) float As[16][132];  // [BK][BM+4]
  __shared__ __align__(16) float Bs[16][68];   // [BK][BN+4]
  const int tid = threadIdx.x;
  const int tr = tid >> 4, tc = tid & 15;
  const int gm0 = blockIdx.x * 128;
  const int n0 = blockIdx.y * 64;

  const int lrow = tid >> 1;        // A-tile row this thread stages
  const int lk0 = (tid & 1) * 8;    // k sub-offset 0 or 8
  const int ln = tid & 63;          // B-tile col
  const int lkb = (tid >> 6) * 4;   // B-tile k base

  const int arow = gm0 + lrow;
  const bool rok = arow < M;

  // gather indices (held in registers for the whole K loop)
  int nb0 = 0, nb1 = 0, nb2 = 0, nb3 = 0, nb4 = 0, nb5 = 0, rb = 0;
  if (MODE == 1 && rok) {
    int aa = b2a[arow];
    rb = b2revb[arow];
    const int* p = a2b + (size_t)aa * 6;
    nb0 = p[0]; nb1 = p[1]; nb2 = p[2]; nb3 = p[3]; nb4 = p[4]; nb5 = p[5];
  }
  if (MODE == 2 && rok) {
    const int* p = a2b + (size_t)arow * 6;
    nb0 = p[0]; nb1 = p[1]; nb2 = p[2]; nb3 = p[3]; nb4 = p[4]; nb5 = p[5];
  }

  float acc[8][4];
#pragma unroll
  for (int i = 0; i < 8; i++)
#pragma unroll
    for (int j = 0; j < 4; j++) acc[i][j] = 0.f;

  for (int kt = 0; kt < K; kt += 16) {
    // ---- stage A tile ----
    const int kbase = kt + lk0;
    float v[8];
    if (!rok) {
#pragma unroll
      for (int i = 0; i < 8; i++) v[i] = 0.f;
    } else if (MODE == 0) {
#pragma unroll
      for (int i = 0; i < 8; i++) {
        int k = kbase + i;
        v[i] = (k < BFD) ? A0[(size_t)arow * BFD + k] : 0.f;
      }
    } else if (MODE == 1) {
      if (kbase + 8 <= BFD) {               // fully in f_bonds segment
#pragma unroll
        for (int i = 0; i < 8; i++) v[i] = A0[(size_t)arow * BFD + kbase + i];
      } else if (kbase >= G1OFS && kbase + 8 <= K1TOT) {  // fully gathered, vectorized
        int kk = kbase - G1OFS;
#pragma unroll
        for (int i = 0; i < 8; i++) v[i] = 0.f;
        acc8bf(msgc + (size_t)nb0 * HH + kk, 1.f, v);
        acc8bf(msgc + (size_t)nb1 * HH + kk, 1.f, v);
        acc8bf(msgc + (size_t)nb2 * HH + kk, 1.f, v);
        acc8bf(msgc + (size_t)nb3 * HH + kk, 1.f, v);
        acc8bf(msgc + (size_t)nb4 * HH + kk, 1.f, v);
        acc8bf(msgc + (size_t)nb5 * HH + kk, 1.f, v);
        acc8bf(msgc + (size_t)rb  * HH + kk, -1.f, v);
      } else {                               // boundary tiles: per-element
#pragma unroll
        for (int i = 0; i < 8; i++) {
          int k = kbase + i;
          float s = 0.f;
          if (k < BFD) s = A0[(size_t)arow * BFD + k];
          else if (k >= G1OFS && k < K1TOT) {
            int kk = k - G1OFS;
            s = bfu(*(const unsigned short*)&msgc[(size_t)nb0 * HH + kk])
              + bfu(*(const unsigned short*)&msgc[(size_t)nb1 * HH + kk])
              + bfu(*(const unsigned short*)&msgc[(size_t)nb2 * HH + kk])
              + bfu(*(const unsigned short*)&msgc[(size_t)nb3 * HH + kk])
              + bfu(*(const unsigned short*)&msgc[(size_t)nb4 * HH + kk])
              + bfu(*(const unsigned short*)&msgc[(size_t)nb5 * HH + kk])
              - bfu(*(const unsigned short*)&msgc[(size_t)rb  * HH + kk]);
          }
          v[i] = s;
        }
      }
    } else {  // MODE 2
      if (kbase + 8 <= AFD) {                // fully f_atoms
#pragma unroll
        for (int i = 0; i < 8; i++) v[i] = A0[(size_t)arow * AFD + kbase + i];
      } else if (kbase >= G2OFS && kbase + 8 <= K2TOT) {  // fully gathered
        int kk = kbase - G2OFS;
#pragma unroll
        for (int i = 0; i < 8; i++) v[i] = 0.f;
        acc8bf(msgc + (size_t)nb0 * HH + kk, 1.f, v);
        acc8bf(msgc + (size_t)nb1 * HH + kk, 1.f, v);
        acc8bf(msgc + (size_t)nb2 * HH + kk, 1.f, v);
        acc8bf(msgc + (size_t)nb3 * HH + kk, 1.f, v);
        acc8bf(msgc + (size_t)nb4 * HH + kk, 1.f, v);
        acc8bf(msgc + (size_t)nb5 * HH + kk, 1.f, v);
      } else {
#pragma unroll
        for (int i = 0; i < 8; i++) {
          int k = kbase + i;
          float s = 0.f;
          if (k < AFD) s = A0[(size_t)arow * AFD + k];
          else if (k >= G2OFS && k < K2TOT) {
            int kk = k - G2OFS;
            s = bfu(*(const unsigned short*)&msgc[(size_t)nb0 * HH + kk])
              + bfu(*(const unsigned short*)&msgc[(size_t)nb1 * HH + kk])
              + bfu(*(const unsigned short*)&msgc[(size_t)nb2 * HH + kk])
              + bfu(*(const unsigned short*)&msgc[(size_t)nb3 * HH + kk])
              + bfu(*(const unsigned short*)&msgc[(size_t)nb4 * HH + kk])
              + bfu(*(const unsigned short*)&msgc[(size_t)nb5 * HH + kk]);
          }
          v[i] = s;
        }
      }
    }
#pragma unroll
    for (int i = 0; i < 8; i++) As[lk0 + i][lrow] = v[i];

    // ---- stage B (weights) tile ----
#pragma unroll
    for (int i = 0; i < 4; i++) {
      int k = kt + lkb + i;
      int n = n0 + ln;
      float w = 0.f;
      if (n < HH && k < K) {
        if (MODE == 0) {
          w = W0[(size_t)k * HH + n];
        } else if (MODE == 1) {
          if (k < BFD) w = W0[(size_t)k * HH + n];
          else if (k >= G1OFS) w = W1[(size_t)(k - G1OFS) * HH + n];
        } else {
          if (k < AFD) w = W0[(size_t)k * HH + n];
          else if (k >= G2OFS) w = W0[(size_t)(k - (G2OFS - AFD)) * HH + n];
        }
      }
      Bs[lkb + i][ln] = w;
    }
    __syncthreads();

    // ---- inner product ----
#pragma unroll
    for (int k = 0; k < 16; k++) {
      float4 b4  = *(const float4*)&Bs[k][tc * 4];
      float4 a0v = *(const float4*)&As[k][tr * 8];
      float4 a1v = *(const float4*)&As[k][tr * 8 + 4];
      float av[8] = {a0v.x, a0v.y, a0v.z, a0v.w, a1v.x, a1v.y, a1v.z, a1v.w};
      float bv[4] = {b4.x, b4.y, b4.z, b4.w};
#pragma unroll
      for (int i = 0; i < 8; i++)
#pragma unroll
        for (int j = 0; j < 4; j++) acc[i][j] += av[i] * bv[j];
    }
    __syncthreads();
  }

  // ---- epilogue ----
#pragma unroll
  for (int i = 0; i < 8; i++) {
    int grow = gm0 + tr * 8 + i;
    if (grow >= M) continue;
#pragma unroll
    for (int j = 0; j < 4; j++) {
      int gcol = n0 + tc * 4 + j;
      if (gcol >= HH) continue;
      size_t o = (size_t)grow * HH + gcol;
      float c = acc[i][j];
      if (MODE == 2) {
        hid_out[o] = fmaxf(c + bias[gcol], 0.f);
      } else {
        float r = fmaxf(c, 0.f);
        if (grow == 0) r = 0.f;
        msg_out[o] = __float2bfloat16(r);
      }
    }
  }
}

// per-molecule mean over sorted mol_id (binary search, no atomics)
__global__ void readout_k(const float* __restrict__ hid, const int* __restrict__ mol_id,
                          float* __restrict__ out, int A)
{
  __shared__ int bnd[2];
  int m = blockIdx.x;
  if (threadIdx.x < 2) {
    int target = m + (int)threadIdx.x;
    int lo = 0, hi = A;
    while (lo < hi) { int mid = (lo + hi) >> 1; if (mol_id[mid] < target) lo = mid + 1; else hi = mid; }
    bnd[threadIdx.x] = lo;
  }
  __syncthreads();
  int s = bnd[0], e = bnd[1];
  int h = threadIdx.x;
  if (h >= HH) return;
  float acc = 0.f;
  for (int a = s; a < e; a++) acc += hid[(size_t)a * HH + h];
  int cnt = e - s; if (cnt < 1) cnt = 1;
  out[(size_t)m * HH + h] = acc / (float)cnt;
}

extern "C" void kernel_launch(void* const* d_in, const int* in_sizes, int n_in,
                              void* d_out, int out_size, void* d_ws, size_t ws_size,
                              hipStream_t stream)
{
  const float* f_atoms[2] = {(const float*)d_in[0], (const float*)d_in[2]};
  const float* f_bonds[2] = {(const float*)d_in[1], (const float*)d_in[3]};
  const float* W_i[2]     = {(const float*)d_in[4], (const float*)d_in[5]};
  const float* W_h[2]     = {(const float*)d_in[6], (const float*)d_in[7]};
  const float* W_o[2]     = {(const float*)d_in[8], (const float*)d_in[10]};
  const float* b_o[2]     = {(const float*)d_in[9], (const float*)d_in[11]};
  const int* a2b[2]    = {(const int*)d_in[12], (const int*)d_in[16]};
  const int* b2a[2]    = {(const int*)d_in[13], (const int*)d_in[17]};
  const int* b2revb[2] = {(const int*)d_in[14], (const int*)d_in[18]};
  const int* mol_id[2] = {(const int*)d_in[15], (const int*)d_in[19]};
  const int A = in_sizes[0] / AFD;   // 100001
  const int B = in_sizes[1] / BFD;   // 200001

  // workspace: region0 = msg0 (bf16 [B,H]); region1 = msg1 (bf16 [B,H]) / hid (f32 [A,H]) overlay
  auto al = [](size_t x){ return (x + 255) & ~(size_t)255; };
  size_t r0 = al((size_t)B * HH * sizeof(bf16));
  size_t r1sz = (size_t)B * HH * sizeof(bf16);
  size_t hsz  = (size_t)A * HH * sizeof(float);
  size_t r1 = al(r1sz > hsz ? r1sz : hsz);
  if (ws_size < r0 + r1) return;  // clean diagnostic failure instead of OOB crash

  char* ws = (char*)d_ws;
  bf16*  msg0 = (bf16*)ws;
  bf16*  msg1 = (bf16*)(ws + r0);
  float* hid  = (float*)(ws + r0);

  dim3 blk(256);
  dim3 gB((B + 127) / 128, 5);   // ceil(300/64)=5 col tiles
  dim3 gA((A + 127) / 128, 5);

  for (int p = 0; p < 2; p++) {
    float* out_p = (float*)d_out + (size_t)p * NMOLS * HH;
    // msg0 = relu(f_bonds @ W_i), row0=0
    gemm_k<0><<<gB, blk, 0, stream>>>(f_bonds[p], W_i[p], nullptr, nullptr, nullptr,
                                      nullptr, nullptr, nullptr, msg0, nullptr, B);
    // msg1 = relu(f_bonds@W_i + gather(msg0)@W_h), row0=0
    gemm_k<1><<<gB, blk, 0, stream>>>(f_bonds[p], W_i[p], W_h[p], b2a[p], b2revb[p],
                                      a2b[p], msg0, nullptr, msg1, nullptr, B);
    // msg0 = relu(f_bonds@W_i + gather(msg1)@W_h), row0=0
    gemm_k<1><<<gB, blk, 0, stream>>>(f_bonds[p], W_i[p], W_h[p], b2a[p], b2revb[p],
                                      a2b[p], msg1, nullptr, msg0, nullptr, B);
    // hid = relu([f_atoms | gather6(msg0)] @ W_o + b_o)
    gemm_k<2><<<gA, blk, 0, stream>>>(f_atoms[p], W_o[p], nullptr, nullptr, nullptr,
                                      a2b[p], msg0, b_o[p], nullptr, hid, A);
    // per-molecule mean readout
    readout_k<<<NMOLS, 320, 0, stream>>>(hid, mol_id[p], out_p, A);
  }
}

// Round 3
// 6101.231 us; speedup vs baseline: 2.5993x; 2.5993x over previous
//
#include <hip/hip_runtime.h>
#include <hip/hip_bf16.h>

typedef __hip_bfloat16 bf16;

#define HH 300     // hidden
#define NMOLS 2000
#define AFD 133    // atom feature dim
#define BFD 147    // bond feature dim
// MODE1 K layout: [0,147) f_bonds@W_i | [147,160) zero | [160,460) gathered@W_h
#define K1TOT 460
#define G1OFS 160
// MODE2 K layout: [0,133) f_atoms | [133,144) zero | [144,444) gathered(a_msg)@W_o-tail
#define K2TOT 444
#define G2OFS 144

// load 4 consecutive bf16 (8B-aligned) and accumulate into s[0..3] with sign
__device__ inline void acc4bf(const bf16* p, float sgn, float* s) {
  uint2 u = *(const uint2*)p;
  union { unsigned u; float f; } c;
  c.u = u.x << 16;         s[0] += sgn * c.f;
  c.u = u.x & 0xffff0000u; s[1] += sgn * c.f;
  c.u = u.y << 16;         s[2] += sgn * c.f;
  c.u = u.y & 0xffff0000u; s[3] += sgn * c.f;
}

// ---------------- Tiled fp32 GEMM, BM=64 x BN=320(full 300) x BK=16, 256 thr ----------------
// Thread (tr=tid>>4, tc=tid&15) computes rows tr*4..+3, cols tc*20..+19. acc[4][20].
// MODE 0: C = f_bonds @ W_i;                        msg_out = relu(C), row0=0
// MODE 1: C = f_bonds@W_i + gather7(msgc)@W_h;      msg_out = relu(C), row0=0
//         gather row r: sum_j msgc[a2b[b2a[r],j]] - msgc[b2revb[r]]
// MODE 2: C = [f_atoms | gather6(msgc)] @ W_o;      hid = relu(C + bias)
template<int MODE>
__global__ __launch_bounds__(256)
void gemm_k(const float* __restrict__ A0, const float* __restrict__ W0,
            const float* __restrict__ W1, const int* __restrict__ b2a,
            const int* __restrict__ b2revb, const int* __restrict__ a2b,
            const bf16* __restrict__ msgc, const float* __restrict__ bias,
            bf16* __restrict__ msg_out, float* __restrict__ hid_out, int M)
{
  constexpr int KTOT = (MODE == 0) ? 160 : (MODE == 1) ? K1TOT : K2TOT;
  __shared__ __align__(16) float As[16][68];   // [BK][BM+4]
  __shared__ __align__(16) float Bs[16][324];  // [BK][BN+4] (stride 324 spreads staging banks)
  const int tid = threadIdx.x;
  const int tr = tid >> 4, tc = tid & 15;
  const int gm0 = blockIdx.x * 64;

  const int lrow = tid >> 2;       // A-stage: row 0..63
  const int lk0 = (tid & 3) * 4;   // A-stage: k quad 0,4,8,12
  const int krow = tid >> 4;       // B-stage: k row 0..15
  const int c0 = (tid & 15) * 20;  // B-stage: col chunk

  const int arow = gm0 + lrow;
  const bool rok = arow < M;

  // gather indices held in registers for the whole K loop
  int nb0 = 0, nb1 = 0, nb2 = 0, nb3 = 0, nb4 = 0, nb5 = 0, rb = 0;
  if (MODE == 1 && rok) {
    int aa = b2a[arow];
    rb = b2revb[arow];
    const int* p = a2b + (size_t)aa * 6;
    nb0 = p[0]; nb1 = p[1]; nb2 = p[2]; nb3 = p[3]; nb4 = p[4]; nb5 = p[5];
  }
  if (MODE == 2 && rok) {
    const int* p = a2b + (size_t)arow * 6;
    nb0 = p[0]; nb1 = p[1]; nb2 = p[2]; nb3 = p[3]; nb4 = p[4]; nb5 = p[5];
  }

  float acc[4][20];
#pragma unroll
  for (int i = 0; i < 4; i++)
#pragma unroll
    for (int j = 0; j < 20; j++) acc[i][j] = 0.f;

  for (int kt = 0; kt < KTOT; kt += 16) {
    // ---- stage A (64 rows x 16 k), 4 elems/thread ----
    const int kbase = kt + lk0;
    float v[4] = {0.f, 0.f, 0.f, 0.f};
    if (rok) {
      if (MODE == 0) {
#pragma unroll
        for (int i = 0; i < 4; i++) {
          int k = kbase + i;
          if (k < BFD) v[i] = A0[(size_t)arow * BFD + k];
        }
      } else if (MODE == 1) {
        if (kbase >= G1OFS) {
          if (kbase + 4 <= K1TOT) {     // gathered quad, 8B-aligned bf16x4
            int kk = kbase - G1OFS;
            acc4bf(msgc + (size_t)nb0 * HH + kk, 1.f, v);
            acc4bf(msgc + (size_t)nb1 * HH + kk, 1.f, v);
            acc4bf(msgc + (size_t)nb2 * HH + kk, 1.f, v);
            acc4bf(msgc + (size_t)nb3 * HH + kk, 1.f, v);
            acc4bf(msgc + (size_t)nb4 * HH + kk, 1.f, v);
            acc4bf(msgc + (size_t)nb5 * HH + kk, 1.f, v);
            acc4bf(msgc + (size_t)rb  * HH + kk, -1.f, v);
          }
        } else {
#pragma unroll
          for (int i = 0; i < 4; i++) {
            int k = kbase + i;
            if (k < BFD) v[i] = A0[(size_t)arow * BFD + k];
          }
        }
      } else {  // MODE 2
        if (kbase >= G2OFS) {
          if (kbase + 4 <= K2TOT) {
            int kk = kbase - G2OFS;
            acc4bf(msgc + (size_t)nb0 * HH + kk, 1.f, v);
            acc4bf(msgc + (size_t)nb1 * HH + kk, 1.f, v);
            acc4bf(msgc + (size_t)nb2 * HH + kk, 1.f, v);
            acc4bf(msgc + (size_t)nb3 * HH + kk, 1.f, v);
            acc4bf(msgc + (size_t)nb4 * HH + kk, 1.f, v);
            acc4bf(msgc + (size_t)nb5 * HH + kk, 1.f, v);
          }
        } else {
#pragma unroll
          for (int i = 0; i < 4; i++) {
            int k = kbase + i;
            if (k < AFD) v[i] = A0[(size_t)arow * AFD + k];
          }
        }
      }
    }
#pragma unroll
    for (int i = 0; i < 4; i++) As[lk0 + i][lrow] = v[i];

    // ---- stage B (16 k x 320 cols), 5 float4 per thread ----
    {
      const int kg = kt + krow;
#pragma unroll
      for (int j = 0; j < 5; j++) {
        const int c = c0 + 4 * j;
        float4 wv = {0.f, 0.f, 0.f, 0.f};
        if (c < HH) {
          if (MODE == 0) {
            if (kg < BFD) wv = *(const float4*)(W0 + (size_t)kg * HH + c);
          } else if (MODE == 1) {
            if (kg < BFD) wv = *(const float4*)(W0 + (size_t)kg * HH + c);
            else if (kg >= G1OFS && kg < K1TOT)
              wv = *(const float4*)(W1 + (size_t)(kg - G1OFS) * HH + c);
          } else {
            if (kg < AFD) wv = *(const float4*)(W0 + (size_t)kg * HH + c);
            else if (kg >= G2OFS && kg < K2TOT)
              wv = *(const float4*)(W0 + (size_t)(kg - (G2OFS - AFD)) * HH + c);
          }
        }
        *(float4*)&Bs[krow][c] = wv;
      }
    }
    __syncthreads();

    // ---- inner product: 80 FMA per k ----
#pragma unroll
    for (int k = 0; k < 16; k++) {
      float4 a4 = *(const float4*)&As[k][tr * 4];
      float a[4] = {a4.x, a4.y, a4.z, a4.w};
#pragma unroll
      for (int j5 = 0; j5 < 5; j5++) {
        float4 b4 = *(const float4*)&Bs[k][tc * 20 + j5 * 4];
        float b[4] = {b4.x, b4.y, b4.z, b4.w};
#pragma unroll
        for (int i = 0; i < 4; i++)
#pragma unroll
          for (int j = 0; j < 4; j++) acc[i][j5 * 4 + j] += a[i] * b[j];
      }
    }
    __syncthreads();
  }

  // ---- epilogue ----
  if (c0 >= HH) return;  // tc=15 pad columns
#pragma unroll
  for (int i = 0; i < 4; i++) {
    int grow = gm0 + tr * 4 + i;
    if (grow >= M) continue;
    if (MODE == 2) {
#pragma unroll
      for (int j5 = 0; j5 < 5; j5++) {
        int c = c0 + 4 * j5;
        float4 bv = *(const float4*)(bias + c);
        float4 o;
        o.x = fmaxf(acc[i][j5 * 4 + 0] + bv.x, 0.f);
        o.y = fmaxf(acc[i][j5 * 4 + 1] + bv.y, 0.f);
        o.z = fmaxf(acc[i][j5 * 4 + 2] + bv.z, 0.f);
        o.w = fmaxf(acc[i][j5 * 4 + 3] + bv.w, 0.f);
        *(float4*)(hid_out + (size_t)grow * HH + c) = o;
      }
    } else {
#pragma unroll
      for (int j5 = 0; j5 < 5; j5++) {
        int c = c0 + 4 * j5;
        bf16 t[4];
#pragma unroll
        for (int j = 0; j < 4; j++) {
          float r = fmaxf(acc[i][j5 * 4 + j], 0.f);
          if (grow == 0) r = 0.f;
          t[j] = __float2bfloat16(r);
        }
        *(uint2*)(msg_out + (size_t)grow * HH + c) = *(const uint2*)t;
      }
    }
  }
}

// per-molecule mean over sorted mol_id (binary search, no atomics)
__global__ void readout_k(const float* __restrict__ hid, const int* __restrict__ mol_id,
                          float* __restrict__ out, int A)
{
  __shared__ int bnd[2];
  int m = blockIdx.x;
  if (threadIdx.x < 2) {
    int target = m + (int)threadIdx.x;
    int lo = 0, hi = A;
    while (lo < hi) { int mid = (lo + hi) >> 1; if (mol_id[mid] < target) lo = mid + 1; else hi = mid; }
    bnd[threadIdx.x] = lo;
  }
  __syncthreads();
  int s = bnd[0], e = bnd[1];
  int h = threadIdx.x;
  if (h >= HH) return;
  float acc = 0.f;
  for (int a = s; a < e; a++) acc += hid[(size_t)a * HH + h];
  int cnt = e - s; if (cnt < 1) cnt = 1;
  out[(size_t)m * HH + h] = acc / (float)cnt;
}

extern "C" void kernel_launch(void* const* d_in, const int* in_sizes, int n_in,
                              void* d_out, int out_size, void* d_ws, size_t ws_size,
                              hipStream_t stream)
{
  const float* f_atoms[2] = {(const float*)d_in[0], (const float*)d_in[2]};
  const float* f_bonds[2] = {(const float*)d_in[1], (const float*)d_in[3]};
  const float* W_i[2]     = {(const float*)d_in[4], (const float*)d_in[5]};
  const float* W_h[2]     = {(const float*)d_in[6], (const float*)d_in[7]};
  const float* W_o[2]     = {(const float*)d_in[8], (const float*)d_in[10]};
  const float* b_o[2]     = {(const float*)d_in[9], (const float*)d_in[11]};
  const int* a2b[2]    = {(const int*)d_in[12], (const int*)d_in[16]};
  const int* b2a[2]    = {(const int*)d_in[13], (const int*)d_in[17]};
  const int* b2revb[2] = {(const int*)d_in[14], (const int*)d_in[18]};
  const int* mol_id[2] = {(const int*)d_in[15], (const int*)d_in[19]};
  const int A = in_sizes[0] / AFD;   // 100001
  const int B = in_sizes[1] / BFD;   // 200001

  // workspace: region0 = msg0 bf16 [B,H]; region1 = msg1 bf16 [B,H] / hid f32 [A,H] overlay
  auto al = [](size_t x){ return (x + 255) & ~(size_t)255; };
  size_t r0 = al((size_t)B * HH * sizeof(bf16));
  size_t r1sz = (size_t)B * HH * sizeof(bf16);
  size_t hsz  = (size_t)A * HH * sizeof(float);
  size_t r1 = al(r1sz > hsz ? r1sz : hsz);
  if (ws_size < r0 + r1) return;  // clean diagnostic failure instead of OOB crash

  char* ws = (char*)d_ws;
  bf16*  msg0 = (bf16*)ws;
  bf16*  msg1 = (bf16*)(ws + r0);
  float* hid  = (float*)(ws + r0);

  dim3 blk(256);
  dim3 gB((B + 63) / 64);
  dim3 gA((A + 63) / 64);

  for (int p = 0; p < 2; p++) {
    float* out_p = (float*)d_out + (size_t)p * NMOLS * HH;
    // msg0 = relu(f_bonds @ W_i), row0=0
    gemm_k<0><<<gB, blk, 0, stream>>>(f_bonds[p], W_i[p], nullptr, nullptr, nullptr,
                                      nullptr, nullptr, nullptr, msg0, nullptr, B);
    // msg1 = relu(f_bonds@W_i + gather7(msg0)@W_h), row0=0
    gemm_k<1><<<gB, blk, 0, stream>>>(f_bonds[p], W_i[p], W_h[p], b2a[p], b2revb[p],
                                      a2b[p], msg0, nullptr, msg1, nullptr, B);
    // msg0 = relu(f_bonds@W_i + gather7(msg1)@W_h), row0=0
    gemm_k<1><<<gB, blk, 0, stream>>>(f_bonds[p], W_i[p], W_h[p], b2a[p], b2revb[p],
                                      a2b[p], msg1, nullptr, msg0, nullptr, B);
    // hid = relu([f_atoms | gather6(msg0)] @ W_o + b_o)
    gemm_k<2><<<gA, blk, 0, stream>>>(f_atoms[p], W_o[p], nullptr, nullptr, nullptr,
                                      a2b[p], msg0, b_o[p], nullptr, hid, A);
    // per-molecule mean readout
    readout_k<<<NMOLS, 320, 0, stream>>>(hid, mol_id[p], out_p, A);
  }
}

// Round 4
// 2438.232 us; speedup vs baseline: 6.5042x; 2.5023x over previous
//
#include <hip/hip_runtime.h>
#include <hip/hip_bf16.h>

typedef __hip_bfloat16 bf16;
typedef __attribute__((ext_vector_type(8))) short bf16x8;
typedef __attribute__((ext_vector_type(4))) float f32x4;

#define HH 300     // hidden
#define NMOLS 2000
#define AFD 133    // atom feature dim
#define BFD 147    // bond feature dim
#define KP 480     // padded K of WT buffers (15 steps of 32)
#define GOFS 160   // gather region starts at k=160 (step 5)
#define NWT (320 * KP)   // elements per WT buffer

// ---- build WT[c][k] bf16: k<fd -> W0[k][c]; 160<=k<460 -> W1[k-160][c]; else 0 ----
__global__ void build_wt(const float* __restrict__ W0, const float* __restrict__ W1,
                         int fd, bf16* __restrict__ WT)
{
  int idx = blockIdx.x * 256 + threadIdx.x;
  if (idx >= NWT) return;
  int c = idx / KP, k = idx - c * KP;
  float v = 0.f;
  if (c < HH) {
    if (k < fd) v = W0[(size_t)k * HH + c];
    else if (k >= GOFS && k < GOFS + HH) v = W1[(size_t)(k - GOFS) * HH + c];
  }
  WT[idx] = __float2bfloat16(v);
}

// ---------------- MFMA GEMM: 64 rows x 320 cols per block, 4 waves split N ----------------
// K layout: steps 0..4 = features (f32, k<FD), steps 5..14 = gathered msg (bf16).
// MODE 0: C = f_bonds @ W_i (5 steps only);           msg_out = relu(C), row0=0
// MODE 1: C = f_bonds@W_i + gather7(msgc)@W_h;        msg_out = relu(C), row0=0
// MODE 2: C = [f_atoms | gather6(msgc)] @ W_o;        hid = relu(C + bias)
template<int MODE>
__global__ __launch_bounds__(256)
void gemm_mfma(const float* __restrict__ A0, const bf16* __restrict__ WT,
               const int* __restrict__ b2a, const int* __restrict__ b2revb,
               const int* __restrict__ a2b, const bf16* __restrict__ msgc,
               const float* __restrict__ bias,
               bf16* __restrict__ msg_out, float* __restrict__ hid_out, int M)
{
  constexpr int KSTEPS = (MODE == 0) ? 5 : 15;
  constexpr int FD = (MODE == 2) ? AFD : BFD;
  constexpr int NB = (MODE == 1) ? 7 : 6;

  __shared__ __align__(16) short As[2][64 * 32];  // [row][32 k] bf16, slot-swizzled

  const int tid = threadIdx.x;
  const int lane = tid & 63;
  const int wave = tid >> 6;
  const int gm0 = blockIdx.x * 64;

  // ---- staging role: thread -> (row, 16B k-slot) ----
  const int sr = tid >> 2;          // row 0..63
  const int ss = tid & 3;           // k slot 0..3 (8 bf16 each)
  const int arow = gm0 + sr;
  const bool rok = arow < M;
  const int sslot = (ss ^ (sr >> 1)) & 3;     // XOR swizzle (<=2-way banks)
  short* stp[2] = { &As[0][sr * 32 + sslot * 8], &As[1][sr * 32 + sslot * 8] };

  int nbi[NB];
  if (MODE == 1) {
    int aa = rok ? b2a[arow] : 0;
    int rv = rok ? b2revb[arow] : 0;
    const int* p = a2b + (size_t)aa * 6;
    if (rok) { nbi[0]=p[0]; nbi[1]=p[1]; nbi[2]=p[2]; nbi[3]=p[3]; nbi[4]=p[4]; nbi[5]=p[5]; }
    else     { nbi[0]=nbi[1]=nbi[2]=nbi[3]=nbi[4]=nbi[5]=0; }
    nbi[6] = rv;
  } else if (MODE == 2) {
    const int* p = a2b + (size_t)arow * 6;
    if (rok) { nbi[0]=p[0]; nbi[1]=p[1]; nbi[2]=p[2]; nbi[3]=p[3]; nbi[4]=p[4]; nbi[5]=p[5]; }
    else     { nbi[0]=nbi[1]=nbi[2]=nbi[3]=nbi[4]=nbi[5]=0; }
  }

  // ---- compute role: A-frag LDS offsets (4 row tiles), B global base ----
  const int crow = lane & 15;       // row within 16-tile / col within 16-tile
  const int kq = lane >> 4;         // k-quad (8 elems)
  int aoff[4];
#pragma unroll
  for (int i = 0; i < 4; i++) {
    int r = i * 16 + crow;
    aoff[i] = r * 32 + ((kq ^ (r >> 1)) & 3) * 8;
  }
  const bf16* bbase = WT + (size_t)(wave * 80 + crow) * KP + kq * 8;

  f32x4 acc[4][5];
#pragma unroll
  for (int i = 0; i < 4; i++)
#pragma unroll
    for (int j = 0; j < 5; j++) acc[i][j] = (f32x4){0.f, 0.f, 0.f, 0.f};

  // ---- staging helpers (issue loads early, convert+write late) ----
  float fv[8];
  uint2 g0[NB], g1[NB];

  auto issue_f = [&](int step) {
    int kb = step * 32 + ss * 8;
#pragma unroll
    for (int j = 0; j < 8; j++) {
      int k = kb + j;
      fv[j] = (rok && k < FD) ? A0[(size_t)arow * FD + k] : 0.f;
    }
  };
  auto finish_f = [&](short* dst) {
    bf16x8 t;
#pragma unroll
    for (int j = 0; j < 8; j++) {
      union { bf16 b; short s; } cv; cv.b = __float2bfloat16(fv[j]); t[j] = cv.s;
    }
    *(bf16x8*)dst = t;
  };
  auto issue_g = [&](int step) {
    int kk = (step - 5) * 32 + ss * 8;
#pragma unroll
    for (int n = 0; n < NB; n++) {
      const char* base = (const char*)msgc + (size_t)nbi[n] * (HH * 2) + kk * 2;
      g0[n] = *(const uint2*)base;
      g1[n] = *(const uint2*)(base + 8);
    }
  };
  auto finish_g = [&](short* dst) {
    float s[8] = {0.f, 0.f, 0.f, 0.f, 0.f, 0.f, 0.f, 0.f};
#pragma unroll
    for (int n = 0; n < NB; n++) {
      float sg = (MODE == 1 && n == 6) ? -1.f : 1.f;
      unsigned w[4] = {g0[n].x, g0[n].y, g1[n].x, g1[n].y};
#pragma unroll
      for (int q = 0; q < 4; q++) {
        union { unsigned u; float f; } lo, hi;
        lo.u = w[q] << 16;
        hi.u = w[q] & 0xffff0000u;
        s[2 * q]     += sg * lo.f;
        s[2 * q + 1] += sg * hi.f;
      }
    }
    bf16x8 t;
#pragma unroll
    for (int j = 0; j < 8; j++) {
      union { bf16 b; short sh; } cv; cv.b = __float2bfloat16(s[j]); t[j] = cv.sh;
    }
    *(bf16x8*)dst = t;
  };

  // ---- main K loop: 1 barrier / step, double-buffered A ----
  issue_f(0);
  finish_f(stp[0]);
  __syncthreads();

  for (int st = 0; st < KSTEPS; st++) {
    const int nxt = st + 1;
    const bool hn = nxt < KSTEPS;
    if (hn) {
      if (MODE != 0 && nxt >= 5) issue_g(nxt); else issue_f(nxt);
    }
    const short* curb = &As[st & 1][0];
    bf16x8 af[4], bfr[5];
#pragma unroll
    for (int i = 0; i < 4; i++) af[i] = *(const bf16x8*)(curb + aoff[i]);
    const bf16* bb = bbase + st * 32;
#pragma unroll
    for (int j = 0; j < 5; j++) bfr[j] = *(const bf16x8*)(bb + (size_t)j * 16 * KP);
#pragma unroll
    for (int j = 0; j < 5; j++)
#pragma unroll
      for (int i = 0; i < 4; i++)
        acc[i][j] = __builtin_amdgcn_mfma_f32_16x16x32_bf16(af[i], bfr[j], acc[i][j], 0, 0, 0);
    if (hn) {
      if (MODE != 0 && nxt >= 5) finish_g(stp[nxt & 1]); else finish_f(stp[nxt & 1]);
    }
    __syncthreads();
  }

  // ---- epilogue: C[row=(kq*4+r within tile i)][col=crow within tile j] ----
#pragma unroll
  for (int j = 0; j < 5; j++) {
    int c = wave * 80 + j * 16 + crow;
    if (c >= HH) continue;
    float bia = (MODE == 2) ? bias[c] : 0.f;
#pragma unroll
    for (int i = 0; i < 4; i++) {
#pragma unroll
      for (int r = 0; r < 4; r++) {
        int g = gm0 + i * 16 + kq * 4 + r;
        if (g >= M) continue;
        float v = acc[i][j][r];
        if (MODE == 2) {
          hid_out[(size_t)g * HH + c] = fmaxf(v + bia, 0.f);
        } else {
          float rv = fmaxf(v, 0.f);
          if (g == 0) rv = 0.f;
          msg_out[(size_t)g * HH + c] = __float2bfloat16(rv);
        }
      }
    }
  }
}

// per-molecule mean over sorted mol_id (binary search, no atomics)
__global__ void readout_k(const float* __restrict__ hid, const int* __restrict__ mol_id,
                          float* __restrict__ out, int A)
{
  __shared__ int bnd[2];
  int m = blockIdx.x;
  if (threadIdx.x < 2) {
    int target = m + (int)threadIdx.x;
    int lo = 0, hi = A;
    while (lo < hi) { int mid = (lo + hi) >> 1; if (mol_id[mid] < target) lo = mid + 1; else hi = mid; }
    bnd[threadIdx.x] = lo;
  }
  __syncthreads();
  int s = bnd[0], e = bnd[1];
  int h = threadIdx.x;
  if (h >= HH) return;
  float acc = 0.f;
  for (int a = s; a < e; a++) acc += hid[(size_t)a * HH + h];
  int cnt = e - s; if (cnt < 1) cnt = 1;
  out[(size_t)m * HH + h] = acc / (float)cnt;
}

extern "C" void kernel_launch(void* const* d_in, const int* in_sizes, int n_in,
                              void* d_out, int out_size, void* d_ws, size_t ws_size,
                              hipStream_t stream)
{
  const float* f_atoms[2] = {(const float*)d_in[0], (const float*)d_in[2]};
  const float* f_bonds[2] = {(const float*)d_in[1], (const float*)d_in[3]};
  const float* W_i[2]     = {(const float*)d_in[4], (const float*)d_in[5]};
  const float* W_h[2]     = {(const float*)d_in[6], (const float*)d_in[7]};
  const float* W_o[2]     = {(const float*)d_in[8], (const float*)d_in[10]};
  const float* b_o[2]     = {(const float*)d_in[9], (const float*)d_in[11]};
  const int* a2b[2]    = {(const int*)d_in[12], (const int*)d_in[16]};
  const int* b2a[2]    = {(const int*)d_in[13], (const int*)d_in[17]};
  const int* b2revb[2] = {(const int*)d_in[14], (const int*)d_in[18]};
  const int* mol_id[2] = {(const int*)d_in[15], (const int*)d_in[19]};
  const int A = in_sizes[0] / AFD;   // 100001
  const int B = in_sizes[1] / BFD;   // 200001

  // ws: msg0 bf16 [B,H] | msg1 bf16 [B,H] overlaid with hid f32 [A,H] | 4x WT bf16
  auto al = [](size_t x){ return (x + 255) & ~(size_t)255; };
  size_t r0 = al((size_t)B * HH * sizeof(bf16));
  size_t r1sz = (size_t)B * HH * sizeof(bf16);
  size_t hsz  = (size_t)A * HH * sizeof(float);
  size_t r1 = al(r1sz > hsz ? r1sz : hsz);
  size_t wtsz = al((size_t)NWT * sizeof(bf16));
  if (ws_size < r0 + r1 + 4 * wtsz) return;  // clean diagnostic fail, no OOB

  char* ws = (char*)d_ws;
  bf16*  msg0 = (bf16*)ws;
  bf16*  msg1 = (bf16*)(ws + r0);
  float* hid  = (float*)(ws + r0);
  bf16* WT1[2] = {(bf16*)(ws + r0 + r1),            (bf16*)(ws + r0 + r1 + wtsz)};
  bf16* WT2[2] = {(bf16*)(ws + r0 + r1 + 2 * wtsz), (bf16*)(ws + r0 + r1 + 3 * wtsz)};

  dim3 blk(256);
  dim3 gW((NWT + 255) / 256);
  dim3 gB((B + 63) / 64);
  dim3 gA((A + 63) / 64);

  for (int p = 0; p < 2; p++) {
    build_wt<<<gW, blk, 0, stream>>>(W_i[p], W_h[p], BFD, WT1[p]);
    build_wt<<<gW, blk, 0, stream>>>(W_o[p], W_o[p] + (size_t)AFD * HH, AFD, WT2[p]);
  }

  for (int p = 0; p < 2; p++) {
    float* out_p = (float*)d_out + (size_t)p * NMOLS * HH;
    // msg0 = relu(f_bonds @ W_i), row0=0
    gemm_mfma<0><<<gB, blk, 0, stream>>>(f_bonds[p], WT1[p], nullptr, nullptr, nullptr,
                                         nullptr, nullptr, msg0, nullptr, B);
    // msg1 = relu(f_bonds@W_i + gather7(msg0)@W_h), row0=0
    gemm_mfma<1><<<gB, blk, 0, stream>>>(f_bonds[p], WT1[p], b2a[p], b2revb[p],
                                         a2b[p], msg0, nullptr, msg1, nullptr, B);
    // msg0 = relu(f_bonds@W_i + gather7(msg1)@W_h), row0=0
    gemm_mfma<1><<<gB, blk, 0, stream>>>(f_bonds[p], WT1[p], b2a[p], b2revb[p],
                                         a2b[p], msg1, nullptr, msg0, nullptr, B);
    // hid = relu([f_atoms | gather6(msg0)] @ W_o + b_o)
    gemm_mfma<2><<<gA, blk, 0, stream>>>(f_atoms[p], WT2[p], nullptr, nullptr,
                                         a2b[p], msg0, b_o[p], nullptr, hid, A);
    // per-molecule mean readout
    readout_k<<<NMOLS, 320, 0, stream>>>(hid, mol_id[p], out_p, A);
  }
}

// Round 5
// 2330.604 us; speedup vs baseline: 6.8046x; 1.0462x over previous
//
#include <hip/hip_runtime.h>
#include <hip/hip_bf16.h>

typedef __hip_bfloat16 bf16;
typedef __attribute__((ext_vector_type(8))) short bf16x8;
typedef __attribute__((ext_vector_type(4))) float f32x4;

#define HH 300     // hidden
#define NMOLS 2000
#define AFD 133    // atom feature dim
#define BFD 147    // bond feature dim
#define KP 480     // padded K of WT buffers (15 steps of 32)
#define GOFS 160   // gather region starts at k=160 (step 5)
#define NWT (320 * KP)   // elements per WT buffer

// ---- build WT[c][k] bf16: k<fd -> W0[k][c]; 160<=k<460 -> W1[k-160][c]; else 0 ----
__global__ void build_wt(const float* __restrict__ W0, const float* __restrict__ W1,
                         int fd, bf16* __restrict__ WT)
{
  int idx = blockIdx.x * 256 + threadIdx.x;
  if (idx >= NWT) return;
  int c = idx / KP, k = idx - c * KP;
  float v = 0.f;
  if (c < HH) {
    if (k < fd) v = W0[(size_t)k * HH + c];
    else if (k >= GOFS && k < GOFS + HH) v = W1[(size_t)(k - GOFS) * HH + c];
  }
  WT[idx] = __float2bfloat16(v);
}

// ---- amsg[a][k] = sum_j msg[a2b[a][j]][k], bf16 out; thread = 4 elems (8B) ----
__global__ __launch_bounds__(256)
void gather6_k(const bf16* __restrict__ msg, const int* __restrict__ a2b,
               bf16* __restrict__ amsg, int A)
{
  int idx = blockIdx.x * 256 + threadIdx.x;
  if (idx >= A * 75) return;
  int a = idx / 75;
  int k4 = (idx - a * 75) * 4;
  const int* p = a2b + (size_t)a * 6;
  float s[4] = {0.f, 0.f, 0.f, 0.f};
#pragma unroll
  for (int j = 0; j < 6; j++) {
    uint2 u = *(const uint2*)(msg + (size_t)p[j] * HH + k4);
    union { unsigned u; float f; } c;
    c.u = u.x << 16;         s[0] += c.f;
    c.u = u.x & 0xffff0000u; s[1] += c.f;
    c.u = u.y << 16;         s[2] += c.f;
    c.u = u.y & 0xffff0000u; s[3] += c.f;
  }
  bf16 t[4];
#pragma unroll
  for (int j = 0; j < 4; j++) t[j] = __float2bfloat16(s[j]);
  *(uint2*)(amsg + (size_t)a * HH + k4) = *(const uint2*)t;
}

// ============ shared GEMM skeleton pieces (64 rows x 320 cols, 4 waves split N) ============
// K layout: steps 0..4 features (k<FD), steps 5..14 gathered (kk = k-160 into [0,300)+pad).
// C/D frag mapping (16x16x32): col=lane&15, row=(lane>>4)*4+reg.

// -------- fallback fused kernel (round-4 proven): 7-row / 6-row gather in-GEMM --------
template<int MODE>
__global__ __launch_bounds__(256)
void gemm_mfma(const float* __restrict__ A0, const bf16* __restrict__ WT,
               const int* __restrict__ b2a, const int* __restrict__ b2revb,
               const int* __restrict__ a2b, const bf16* __restrict__ msgc,
               const float* __restrict__ bias,
               bf16* __restrict__ msg_out, float* __restrict__ hid_out, int M)
{
  constexpr int KSTEPS = (MODE == 0) ? 5 : 15;
  constexpr int FD = (MODE == 2) ? AFD : BFD;
  constexpr int NB = (MODE == 1) ? 7 : 6;

  __shared__ __align__(16) short As[2][64 * 32];

  const int tid = threadIdx.x;
  const int lane = tid & 63;
  const int wave = tid >> 6;
  const int gm0 = blockIdx.x * 64;

  const int sr = tid >> 2;
  const int ss = tid & 3;
  const int arow = gm0 + sr;
  const bool rok = arow < M;
  const int sslot = (ss ^ (sr >> 1)) & 3;
  short* stp[2] = { &As[0][sr * 32 + sslot * 8], &As[1][sr * 32 + sslot * 8] };

  int nbi[NB];
  if (MODE == 1) {
    int aa = rok ? b2a[arow] : 0;
    int rv = rok ? b2revb[arow] : 0;
    const int* p = a2b + (size_t)aa * 6;
    if (rok) { nbi[0]=p[0]; nbi[1]=p[1]; nbi[2]=p[2]; nbi[3]=p[3]; nbi[4]=p[4]; nbi[5]=p[5]; }
    else     { nbi[0]=nbi[1]=nbi[2]=nbi[3]=nbi[4]=nbi[5]=0; }
    nbi[6] = rv;
  } else if (MODE == 2) {
    const int* p = a2b + (size_t)arow * 6;
    if (rok) { nbi[0]=p[0]; nbi[1]=p[1]; nbi[2]=p[2]; nbi[3]=p[3]; nbi[4]=p[4]; nbi[5]=p[5]; }
    else     { nbi[0]=nbi[1]=nbi[2]=nbi[3]=nbi[4]=nbi[5]=0; }
  }

  const int crow = lane & 15;
  const int kq = lane >> 4;
  int aoff[4];
#pragma unroll
  for (int i = 0; i < 4; i++) {
    int r = i * 16 + crow;
    aoff[i] = r * 32 + ((kq ^ (r >> 1)) & 3) * 8;
  }
  const bf16* bbase = WT + (size_t)(wave * 80 + crow) * KP + kq * 8;

  f32x4 acc[4][5];
#pragma unroll
  for (int i = 0; i < 4; i++)
#pragma unroll
    for (int j = 0; j < 5; j++) acc[i][j] = (f32x4){0.f, 0.f, 0.f, 0.f};

  float fv[8];
  uint2 g0[NB], g1[NB];

  auto issue_f = [&](int step) {
    int kb = step * 32 + ss * 8;
#pragma unroll
    for (int j = 0; j < 8; j++) {
      int k = kb + j;
      fv[j] = (rok && k < FD) ? A0[(size_t)arow * FD + k] : 0.f;
    }
  };
  auto finish_f = [&](short* dst) {
    bf16x8 t;
#pragma unroll
    for (int j = 0; j < 8; j++) {
      union { bf16 b; short s; } cv; cv.b = __float2bfloat16(fv[j]); t[j] = cv.s;
    }
    *(bf16x8*)dst = t;
  };
  auto issue_g = [&](int step) {
    int kk = (step - 5) * 32 + ss * 8;
#pragma unroll
    for (int n = 0; n < NB; n++) {
      const char* base = (const char*)msgc + ((size_t)nbi[n] * HH + kk) * 2;
      g0[n] = *(const uint2*)base;
      g1[n] = *(const uint2*)(base + 8);
    }
  };
  auto finish_g = [&](short* dst) {
    float s[8] = {0.f, 0.f, 0.f, 0.f, 0.f, 0.f, 0.f, 0.f};
#pragma unroll
    for (int n = 0; n < NB; n++) {
      float sg = (MODE == 1 && n == 6) ? -1.f : 1.f;
      unsigned w[4] = {g0[n].x, g0[n].y, g1[n].x, g1[n].y};
#pragma unroll
      for (int q = 0; q < 4; q++) {
        union { unsigned u; float f; } lo, hi;
        lo.u = w[q] << 16;
        hi.u = w[q] & 0xffff0000u;
        s[2 * q]     += sg * lo.f;
        s[2 * q + 1] += sg * hi.f;
      }
    }
    bf16x8 t;
#pragma unroll
    for (int j = 0; j < 8; j++) {
      union { bf16 b; short sh; } cv; cv.b = __float2bfloat16(s[j]); t[j] = cv.sh;
    }
    *(bf16x8*)dst = t;
  };

  issue_f(0);
  finish_f(stp[0]);
  __syncthreads();

  for (int st = 0; st < KSTEPS; st++) {
    const int nxt = st + 1;
    const bool hn = nxt < KSTEPS;
    if (hn) {
      if (MODE != 0 && nxt >= 5) issue_g(nxt); else issue_f(nxt);
    }
    const short* curb = &As[st & 1][0];
    bf16x8 af[4], bfr[5];
#pragma unroll
    for (int i = 0; i < 4; i++) af[i] = *(const bf16x8*)(curb + aoff[i]);
    const bf16* bb = bbase + st * 32;
#pragma unroll
    for (int j = 0; j < 5; j++) bfr[j] = *(const bf16x8*)(bb + (size_t)j * 16 * KP);
#pragma unroll
    for (int j = 0; j < 5; j++)
#pragma unroll
      for (int i = 0; i < 4; i++)
        acc[i][j] = __builtin_amdgcn_mfma_f32_16x16x32_bf16(af[i], bfr[j], acc[i][j], 0, 0, 0);
    if (hn) {
      if (MODE != 0 && nxt >= 5) finish_g(stp[nxt & 1]); else finish_f(stp[nxt & 1]);
    }
    __syncthreads();
  }

#pragma unroll
  for (int j = 0; j < 5; j++) {
    int c = wave * 80 + j * 16 + crow;
    if (c >= HH) continue;
    float bia = (MODE == 2) ? bias[c] : 0.f;
#pragma unroll
    for (int i = 0; i < 4; i++) {
#pragma unroll
      for (int r = 0; r < 4; r++) {
        int g = gm0 + i * 16 + kq * 4 + r;
        if (g >= M) continue;
        float v = acc[i][j][r];
        if (MODE == 2) {
          hid_out[(size_t)g * HH + c] = fmaxf(v + bia, 0.f);
        } else {
          float rv = fmaxf(v, 0.f);
          if (g == 0) rv = 0.f;
          msg_out[(size_t)g * HH + c] = __float2bfloat16(rv);
        }
      }
    }
  }
}

// -------- amsg-based GEMM: MODE 1: A = f_bonds | (amsg[b2a[r]] - msg[b2revb[r]])
//                           MODE 2: A = f_atoms | amsg[r] --------
template<int MODE>
__global__ __launch_bounds__(256)
void gemm_mfma2(const float* __restrict__ A0, const bf16* __restrict__ WT,
                const int* __restrict__ b2a, const int* __restrict__ b2revb,
                const bf16* __restrict__ amsg, const bf16* __restrict__ msgc,
                const float* __restrict__ bias,
                bf16* __restrict__ msg_out, float* __restrict__ hid_out, int M)
{
  constexpr int KSTEPS = 15;
  constexpr int FD = (MODE == 2) ? AFD : BFD;

  __shared__ __align__(16) short As[2][64 * 32];

  const int tid = threadIdx.x;
  const int lane = tid & 63;
  const int wave = tid >> 6;
  const int gm0 = blockIdx.x * 64;

  const int sr = tid >> 2;
  const int ss = tid & 3;
  const int arow = gm0 + sr;
  const bool rok = arow < M;
  const int sslot = (ss ^ (sr >> 1)) & 3;
  short* stp[2] = { &As[0][sr * 32 + sslot * 8], &As[1][sr * 32 + sslot * 8] };

  int ba = 0, rb = 0;
  if (MODE == 1) {
    ba = rok ? b2a[arow] : 0;
    rb = rok ? b2revb[arow] : 0;
  }

  const int crow = lane & 15;
  const int kq = lane >> 4;
  int aoff[4];
#pragma unroll
  for (int i = 0; i < 4; i++) {
    int r = i * 16 + crow;
    aoff[i] = r * 32 + ((kq ^ (r >> 1)) & 3) * 8;
  }
  const bf16* bbase = WT + (size_t)(wave * 80 + crow) * KP + kq * 8;

  f32x4 acc[4][5];
#pragma unroll
  for (int i = 0; i < 4; i++)
#pragma unroll
    for (int j = 0; j < 5; j++) acc[i][j] = (f32x4){0.f, 0.f, 0.f, 0.f};

  float fv[8];
  uint2 ga0, ga1, gb0, gb1;

  auto issue_f = [&](int step) {
    int kb = step * 32 + ss * 8;
#pragma unroll
    for (int j = 0; j < 8; j++) {
      int k = kb + j;
      fv[j] = (rok && k < FD) ? A0[(size_t)arow * FD + k] : 0.f;
    }
  };
  auto finish_f = [&](short* dst) {
    bf16x8 t;
#pragma unroll
    for (int j = 0; j < 8; j++) {
      union { bf16 b; short s; } cv; cv.b = __float2bfloat16(fv[j]); t[j] = cv.s;
    }
    *(bf16x8*)dst = t;
  };
  auto issue_g = [&](int step) {
    int kk = (step - 5) * 32 + ss * 8;
    const char* pa = (const char*)amsg + ((size_t)(MODE == 1 ? ba : arow) * HH + kk) * 2;
    ga0 = *(const uint2*)pa;
    ga1 = *(const uint2*)(pa + 8);
    if (MODE == 1) {
      const char* pb = (const char*)msgc + ((size_t)rb * HH + kk) * 2;
      gb0 = *(const uint2*)pb;
      gb1 = *(const uint2*)(pb + 8);
    }
  };
  auto finish_g = [&](short* dst) {
    if (MODE == 2) {
      *(uint2*)dst = ga0;
      *(uint2*)(dst + 4) = ga1;
    } else {
      unsigned wa[4] = {ga0.x, ga0.y, ga1.x, ga1.y};
      unsigned wb[4] = {gb0.x, gb0.y, gb1.x, gb1.y};
      bf16x8 t;
#pragma unroll
      for (int q = 0; q < 4; q++) {
        union { unsigned u; float f; } alo, ahi, blo, bhi;
        alo.u = wa[q] << 16;         blo.u = wb[q] << 16;
        ahi.u = wa[q] & 0xffff0000u; bhi.u = wb[q] & 0xffff0000u;
        union { bf16 b; short s; } c0, c1;
        c0.b = __float2bfloat16(alo.f - blo.f);
        c1.b = __float2bfloat16(ahi.f - bhi.f);
        t[2 * q] = c0.s; t[2 * q + 1] = c1.s;
      }
      *(bf16x8*)dst = t;
    }
  };

  issue_f(0);
  finish_f(stp[0]);
  __syncthreads();

  for (int st = 0; st < KSTEPS; st++) {
    const int nxt = st + 1;
    const bool hn = nxt < KSTEPS;
    if (hn) {
      if (nxt >= 5) issue_g(nxt); else issue_f(nxt);
    }
    const short* curb = &As[st & 1][0];
    bf16x8 af[4], bfr[5];
#pragma unroll
    for (int i = 0; i < 4; i++) af[i] = *(const bf16x8*)(curb + aoff[i]);
    const bf16* bb = bbase + st * 32;
#pragma unroll
    for (int j = 0; j < 5; j++) bfr[j] = *(const bf16x8*)(bb + (size_t)j * 16 * KP);
#pragma unroll
    for (int j = 0; j < 5; j++)
#pragma unroll
      for (int i = 0; i < 4; i++)
        acc[i][j] = __builtin_amdgcn_mfma_f32_16x16x32_bf16(af[i], bfr[j], acc[i][j], 0, 0, 0);
    if (hn) {
      if (nxt >= 5) finish_g(stp[nxt & 1]); else finish_f(stp[nxt & 1]);
    }
    __syncthreads();
  }

#pragma unroll
  for (int j = 0; j < 5; j++) {
    int c = wave * 80 + j * 16 + crow;
    if (c >= HH) continue;
    float bia = (MODE == 2) ? bias[c] : 0.f;
#pragma unroll
    for (int i = 0; i < 4; i++) {
#pragma unroll
      for (int r = 0; r < 4; r++) {
        int g = gm0 + i * 16 + kq * 4 + r;
        if (g >= M) continue;
        float v = acc[i][j][r];
        if (MODE == 2) {
          hid_out[(size_t)g * HH + c] = fmaxf(v + bia, 0.f);
        } else {
          float rv = fmaxf(v, 0.f);
          if (g == 0) rv = 0.f;
          msg_out[(size_t)g * HH + c] = __float2bfloat16(rv);
        }
      }
    }
  }
}

// per-molecule mean over sorted mol_id (binary search, no atomics)
__global__ void readout_k(const float* __restrict__ hid, const int* __restrict__ mol_id,
                          float* __restrict__ out, int A)
{
  __shared__ int bnd[2];
  int m = blockIdx.x;
  if (threadIdx.x < 2) {
    int target = m + (int)threadIdx.x;
    int lo = 0, hi = A;
    while (lo < hi) { int mid = (lo + hi) >> 1; if (mol_id[mid] < target) lo = mid + 1; else hi = mid; }
    bnd[threadIdx.x] = lo;
  }
  __syncthreads();
  int s = bnd[0], e = bnd[1];
  int h = threadIdx.x;
  if (h >= HH) return;
  float acc = 0.f;
  for (int a = s; a < e; a++) acc += hid[(size_t)a * HH + h];
  int cnt = e - s; if (cnt < 1) cnt = 1;
  out[(size_t)m * HH + h] = acc / (float)cnt;
}

extern "C" void kernel_launch(void* const* d_in, const int* in_sizes, int n_in,
                              void* d_out, int out_size, void* d_ws, size_t ws_size,
                              hipStream_t stream)
{
  const float* f_atoms[2] = {(const float*)d_in[0], (const float*)d_in[2]};
  const float* f_bonds[2] = {(const float*)d_in[1], (const float*)d_in[3]};
  const float* W_i[2]     = {(const float*)d_in[4], (const float*)d_in[5]};
  const float* W_h[2]     = {(const float*)d_in[6], (const float*)d_in[7]};
  const float* W_o[2]     = {(const float*)d_in[8], (const float*)d_in[10]};
  const float* b_o[2]     = {(const float*)d_in[9], (const float*)d_in[11]};
  const int* a2b[2]    = {(const int*)d_in[12], (const int*)d_in[16]};
  const int* b2a[2]    = {(const int*)d_in[13], (const int*)d_in[17]};
  const int* b2revb[2] = {(const int*)d_in[14], (const int*)d_in[18]};
  const int* mol_id[2] = {(const int*)d_in[15], (const int*)d_in[19]};
  const int A = in_sizes[0] / AFD;   // 100001
  const int B = in_sizes[1] / BFD;   // 200001

  // ws: msg0 bf16[B,H] | msg1 bf16[B,H]/hid f32[A,H] | amsg bf16[A,H] (optional) | 4x WT
  auto al = [](size_t x){ return (x + 255) & ~(size_t)255; };
  size_t r0 = al((size_t)B * HH * sizeof(bf16));
  size_t r1sz = (size_t)B * HH * sizeof(bf16);
  size_t hsz  = (size_t)A * HH * sizeof(float);
  size_t r1 = al(r1sz > hsz ? r1sz : hsz);
  size_t amsz = al((size_t)A * HH * sizeof(bf16));
  size_t wtsz = al((size_t)NWT * sizeof(bf16));
  if (ws_size < r0 + r1 + 4 * wtsz) return;  // clean diagnostic fail
  const bool big = ws_size >= r0 + r1 + amsz + 4 * wtsz;  // amsg path available?

  char* ws = (char*)d_ws;
  bf16*  msg0 = (bf16*)ws;
  bf16*  msg1 = (bf16*)(ws + r0);
  float* hid  = (float*)(ws + r0);
  size_t wofs = big ? (r0 + r1 + amsz) : (r0 + r1);
  bf16*  amsg = (bf16*)(ws + r0 + r1);
  bf16* WT1[2] = {(bf16*)(ws + wofs),            (bf16*)(ws + wofs + wtsz)};
  bf16* WT2[2] = {(bf16*)(ws + wofs + 2 * wtsz), (bf16*)(ws + wofs + 3 * wtsz)};

  dim3 blk(256);
  dim3 gW((NWT + 255) / 256);
  dim3 gB((B + 63) / 64);
  dim3 gA((A + 63) / 64);
  dim3 gG((A * 75 + 255) / 256);

  for (int p = 0; p < 2; p++) {
    build_wt<<<gW, blk, 0, stream>>>(W_i[p], W_h[p], BFD, WT1[p]);
    build_wt<<<gW, blk, 0, stream>>>(W_o[p], W_o[p] + (size_t)AFD * HH, AFD, WT2[p]);
  }

  for (int p = 0; p < 2; p++) {
    float* out_p = (float*)d_out + (size_t)p * NMOLS * HH;
    // msg0 = relu(f_bonds @ W_i), row0=0
    gemm_mfma<0><<<gB, blk, 0, stream>>>(f_bonds[p], WT1[p], nullptr, nullptr, nullptr,
                                         nullptr, nullptr, msg0, nullptr, B);
    if (big) {
      gather6_k<<<gG, blk, 0, stream>>>(msg0, a2b[p], amsg, A);
      gemm_mfma2<1><<<gB, blk, 0, stream>>>(f_bonds[p], WT1[p], b2a[p], b2revb[p],
                                            amsg, msg0, nullptr, msg1, nullptr, B);
      gather6_k<<<gG, blk, 0, stream>>>(msg1, a2b[p], amsg, A);
      gemm_mfma2<1><<<gB, blk, 0, stream>>>(f_bonds[p], WT1[p], b2a[p], b2revb[p],
                                            amsg, msg1, nullptr, msg0, nullptr, B);
      gather6_k<<<gG, blk, 0, stream>>>(msg0, a2b[p], amsg, A);
      gemm_mfma2<2><<<gA, blk, 0, stream>>>(f_atoms[p], WT2[p], nullptr, nullptr,
                                            amsg, nullptr, b_o[p], nullptr, hid, A);
    } else {
      gemm_mfma<1><<<gB, blk, 0, stream>>>(f_bonds[p], WT1[p], b2a[p], b2revb[p],
                                           a2b[p], msg0, nullptr, msg1, nullptr, B);
      gemm_mfma<1><<<gB, blk, 0, stream>>>(f_bonds[p], WT1[p], b2a[p], b2revb[p],
                                           a2b[p], msg1, nullptr, msg0, nullptr, B);
      gemm_mfma<2><<<gA, blk, 0, stream>>>(f_atoms[p], WT2[p], nullptr, nullptr,
                                           a2b[p], msg0, b_o[p], nullptr, hid, A);
    }
    readout_k<<<NMOLS, 320, 0, stream>>>(hid, mol_id[p], out_p, A);
  }
}

// Round 6
// 2125.732 us; speedup vs baseline: 7.4604x; 1.0964x over previous
//
#include <hip/hip_runtime.h>
#include <hip/hip_bf16.h>

typedef __hip_bfloat16 bf16;
typedef __attribute__((ext_vector_type(8))) short bf16x8;
typedef __attribute__((ext_vector_type(4))) float f32x4;

#define HH 300     // hidden
#define NMOLS 2000
#define AFD 133    // atom feature dim
#define BFD 147    // bond feature dim
#define KP 480     // padded K of WT buffers (15 steps of 32)
#define GOFS 160   // gather region starts at k=160 (step 5)
#define NWT (320 * KP)   // elements per WT buffer

// ---- build WT[c][k] bf16: k<fd -> W0[k][c]; 160<=k<460 -> W1[k-160][c]; else 0 ----
__global__ void build_wt(const float* __restrict__ W0, const float* __restrict__ W1,
                         int fd, bf16* __restrict__ WT)
{
  int idx = blockIdx.x * 256 + threadIdx.x;
  if (idx >= NWT) return;
  int c = idx / KP, k = idx - c * KP;
  float v = 0.f;
  if (c < HH) {
    if (k < fd) v = W0[(size_t)k * HH + c];
    else if (k >= GOFS && k < GOFS + HH) v = W1[(size_t)(k - GOFS) * HH + c];
  }
  WT[idx] = __float2bfloat16(v);
}

// ---- amsg[a][k] = sum_j msg[a2b[a][j]][k], bf16; thread = 4 elems (8B loads) ----
__global__ __launch_bounds__(256)
void gather6_k(const bf16* __restrict__ msg, const int* __restrict__ a2b,
               bf16* __restrict__ amsg, int A)
{
  int idx = blockIdx.x * 256 + threadIdx.x;
  if (idx >= A * 75) return;
  int a = idx / 75;
  int k4 = (idx - a * 75) * 4;
  const int* p = a2b + (size_t)a * 6;
  float s[4] = {0.f, 0.f, 0.f, 0.f};
#pragma unroll
  for (int j = 0; j < 6; j++) {
    uint2 u = *(const uint2*)(msg + (size_t)p[j] * HH + k4);
    union { unsigned u; float f; } c;
    c.u = u.x << 16;         s[0] += c.f;
    c.u = u.x & 0xffff0000u; s[1] += c.f;
    c.u = u.y << 16;         s[2] += c.f;
    c.u = u.y & 0xffff0000u; s[3] += c.f;
  }
  bf16 t[4];
#pragma unroll
  for (int j = 0; j < 4; j++) t[j] = __float2bfloat16(s[j]);
  *(uint2*)(amsg + (size_t)a * HH + k4) = *(const uint2*)t;
}

// ============ deep-pipelined MFMA GEMM: 64 rows x 320 cols, 4 waves split N ============
// K layout: steps 0..4 features (k<FD from A0, f32), steps 5..14 gathered bf16.
// MODE 0: C = f_bonds @ W_i (5 steps);                      msg_out = relu(C), row0=0
// MODE 1: A tail = amsg[b2a[r]] - msg[b2revb[r]];           msg_out = relu(C), row0=0
// MODE 2: A tail = amsg[r];                                 hid = relu(C + bias)
// Pipeline: issue(s+3) / compute(s) / finish(s+1); raw s_barrier + lgkmcnt(0) only,
// so prefetched global loads stay in flight across barriers (counted vmcnt).
template<int MODE>
__global__ __launch_bounds__(256)
void gemm_p(const float* __restrict__ A0, const bf16* __restrict__ WT,
            const int* __restrict__ b2a, const int* __restrict__ b2revb,
            const bf16* __restrict__ amsg, const bf16* __restrict__ msgc,
            const float* __restrict__ bias,
            bf16* __restrict__ msg_out, float* __restrict__ hid_out, int M)
{
  constexpr int KSTEPS = (MODE == 0) ? 5 : 15;
  constexpr int FD = (MODE == 2) ? AFD : BFD;

  __shared__ __align__(16) short As[4][64 * 32];   // 4-deep ring, 4KB each

  const int tid = threadIdx.x;
  const int lane = tid & 63;
  const int wave = tid >> 6;
  const int gm0 = blockIdx.x * 64;

  // staging role: 4 threads per row, 8 bf16 (16B) per thread per step
  const int sr = tid >> 2;
  const int ss = tid & 3;
  const int arow = gm0 + sr;
  const bool rok = arow < M;
  const int stoff = sr * 32 + (((ss ^ (sr >> 1)) & 3)) * 8;  // XOR-swizzled slot

  int ba = 0, rb = 0;
  if (MODE == 1) {
    ba = rok ? b2a[arow] : 0;
    rb = rok ? b2revb[arow] : 0;
  }

  // compute role: A-frag LDS offsets (4 row tiles), B global base
  const int crow = lane & 15;
  const int kq = lane >> 4;
  int aoff[4];
#pragma unroll
  for (int i = 0; i < 4; i++) {
    int r = i * 16 + crow;
    aoff[i] = r * 32 + ((kq ^ (r >> 1)) & 3) * 8;
  }
  const bf16* bbase = WT + (size_t)(wave * 80 + crow) * KP + kq * 8;

  f32x4 acc[4][5];
#pragma unroll
  for (int i = 0; i < 4; i++)
#pragma unroll
    for (int j = 0; j < 5; j++) acc[i][j] = (f32x4){0.f, 0.f, 0.f, 0.f};

  // 3 in-flight register sets (prefetch distance 3); statically indexed via unroll
  float fv[3][8];
  uint2 ga[3][2], gb[3][2];

  auto issue = [&](int s) {
    const int set = s % 3;
    if (s < 5) {
      int kb = s * 32 + ss * 8;
#pragma unroll
      for (int j = 0; j < 8; j++) {
        int k = kb + j;
        fv[set][j] = (rok && k < FD) ? A0[(size_t)arow * FD + k] : 0.f;
      }
    } else {
      int kk = (s - 5) * 32 + ss * 8;
      const char* pa = (const char*)amsg + ((size_t)(MODE == 1 ? ba : arow) * HH + kk) * 2;
      ga[set][0] = *(const uint2*)pa;
      ga[set][1] = *(const uint2*)(pa + 8);
      if (MODE == 1) {
        const char* pb = (const char*)msgc + ((size_t)rb * HH + kk) * 2;
        gb[set][0] = *(const uint2*)pb;
        gb[set][1] = *(const uint2*)(pb + 8);
      }
    }
  };

  auto finish = [&](int s) {
    const int set = s % 3;
    short* dst = &As[s & 3][stoff];
    if (s < 5) {
      bf16x8 t;
#pragma unroll
      for (int j = 0; j < 8; j++) {
        union { bf16 b; short sh; } cv; cv.b = __float2bfloat16(fv[set][j]); t[j] = cv.sh;
      }
      *(bf16x8*)dst = t;
    } else if (MODE == 2) {
      *(uint2*)dst = ga[set][0];
      *(uint2*)(dst + 4) = ga[set][1];
    } else {
      unsigned wa[4] = {ga[set][0].x, ga[set][0].y, ga[set][1].x, ga[set][1].y};
      unsigned wb[4] = {gb[set][0].x, gb[set][0].y, gb[set][1].x, gb[set][1].y};
      bf16x8 t;
#pragma unroll
      for (int q = 0; q < 4; q++) {
        union { unsigned u; float f; } alo, ahi, blo, bhi;
        alo.u = wa[q] << 16;         blo.u = wb[q] << 16;
        ahi.u = wa[q] & 0xffff0000u; bhi.u = wb[q] & 0xffff0000u;
        union { bf16 b; short sh; } c0, c1;
        c0.b = __float2bfloat16(alo.f - blo.f);
        c1.b = __float2bfloat16(ahi.f - bhi.f);
        t[2 * q] = c0.sh; t[2 * q + 1] = c1.sh;
      }
      *(bf16x8*)dst = t;
    }
  };

  // ---- prologue: fill pipeline (depth 3), stage step 0 ----
  issue(0); issue(1); issue(2);
  finish(0);
  asm volatile("s_waitcnt lgkmcnt(0)" ::: "memory");
  __builtin_amdgcn_s_barrier();

  // ---- main loop: one raw barrier per step, loads in flight across it ----
#pragma unroll
  for (int s = 0; s < KSTEPS; s++) {
    if (s + 3 < KSTEPS) issue(s + 3);

    // compute step s from As[s&3]
    {
      const short* curb = &As[s & 3][0];
      bf16x8 af[4], bfr[5];
#pragma unroll
      for (int i = 0; i < 4; i++) af[i] = *(const bf16x8*)(curb + aoff[i]);
      const bf16* bb = bbase + s * 32;
#pragma unroll
      for (int j = 0; j < 5; j++) bfr[j] = *(const bf16x8*)(bb + (size_t)j * 16 * KP);
#pragma unroll
      for (int j = 0; j < 5; j++)
#pragma unroll
        for (int i = 0; i < 4; i++)
          acc[i][j] = __builtin_amdgcn_mfma_f32_16x16x32_bf16(af[i], bfr[j], acc[i][j], 0, 0, 0);
    }

    if (s + 1 < KSTEPS) {
      finish(s + 1);   // counted vmcnt wait on loads issued 3 steps ago
      asm volatile("s_waitcnt lgkmcnt(0)" ::: "memory");
      __builtin_amdgcn_s_barrier();
    }
  }

  // ---- epilogue: C/D frag col=lane&15, row=(lane>>4)*4+reg ----
#pragma unroll
  for (int j = 0; j < 5; j++) {
    int c = wave * 80 + j * 16 + crow;
    if (c >= HH) continue;
    float bia = (MODE == 2) ? bias[c] : 0.f;
#pragma unroll
    for (int i = 0; i < 4; i++) {
#pragma unroll
      for (int r = 0; r < 4; r++) {
        int g = gm0 + i * 16 + kq * 4 + r;
        if (g >= M) continue;
        float v = acc[i][j][r];
        if (MODE == 2) {
          hid_out[(size_t)g * HH + c] = fmaxf(v + bia, 0.f);
        } else {
          float rv = fmaxf(v, 0.f);
          if (g == 0) rv = 0.f;
          msg_out[(size_t)g * HH + c] = __float2bfloat16(rv);
        }
      }
    }
  }
}

// per-molecule mean over sorted mol_id (binary search, no atomics)
__global__ void readout_k(const float* __restrict__ hid, const int* __restrict__ mol_id,
                          float* __restrict__ out, int A)
{
  __shared__ int bnd[2];
  int m = blockIdx.x;
  if (threadIdx.x < 2) {
    int target = m + (int)threadIdx.x;
    int lo = 0, hi = A;
    while (lo < hi) { int mid = (lo + hi) >> 1; if (mol_id[mid] < target) lo = mid + 1; else hi = mid; }
    bnd[threadIdx.x] = lo;
  }
  __syncthreads();
  int s = bnd[0], e = bnd[1];
  int h = threadIdx.x;
  if (h >= HH) return;
  float acc = 0.f;
  for (int a = s; a < e; a++) acc += hid[(size_t)a * HH + h];
  int cnt = e - s; if (cnt < 1) cnt = 1;
  out[(size_t)m * HH + h] = acc / (float)cnt;
}

extern "C" void kernel_launch(void* const* d_in, const int* in_sizes, int n_in,
                              void* d_out, int out_size, void* d_ws, size_t ws_size,
                              hipStream_t stream)
{
  const float* f_atoms[2] = {(const float*)d_in[0], (const float*)d_in[2]};
  const float* f_bonds[2] = {(const float*)d_in[1], (const float*)d_in[3]};
  const float* W_i[2]     = {(const float*)d_in[4], (const float*)d_in[5]};
  const float* W_h[2]     = {(const float*)d_in[6], (const float*)d_in[7]};
  const float* W_o[2]     = {(const float*)d_in[8], (const float*)d_in[10]};
  const float* b_o[2]     = {(const float*)d_in[9], (const float*)d_in[11]};
  const int* a2b[2]    = {(const int*)d_in[12], (const int*)d_in[16]};
  const int* b2a[2]    = {(const int*)d_in[13], (const int*)d_in[17]};
  const int* b2revb[2] = {(const int*)d_in[14], (const int*)d_in[18]};
  const int* mol_id[2] = {(const int*)d_in[15], (const int*)d_in[19]};
  const int A = in_sizes[0] / AFD;   // 100001
  const int B = in_sizes[1] / BFD;   // 200001

  // ws: msg0 bf16[B,H] | msg1 bf16[B,H]/hid f32[A,H] | amsg bf16[A,H] | 4x WT
  auto al = [](size_t x){ return (x + 255) & ~(size_t)255; };
  size_t r0 = al((size_t)B * HH * sizeof(bf16));
  size_t r1sz = (size_t)B * HH * sizeof(bf16);
  size_t hsz  = (size_t)A * HH * sizeof(float);
  size_t r1 = al(r1sz > hsz ? r1sz : hsz);
  size_t amsz = al((size_t)A * HH * sizeof(bf16));
  size_t wtsz = al((size_t)NWT * sizeof(bf16));
  if (ws_size < r0 + r1 + amsz + 4 * wtsz) return;  // proven available in round 5

  char* ws = (char*)d_ws;
  bf16*  msg0 = (bf16*)ws;
  bf16*  msg1 = (bf16*)(ws + r0);
  float* hid  = (float*)(ws + r0);
  bf16*  amsg = (bf16*)(ws + r0 + r1);
  size_t wofs = r0 + r1 + amsz;
  bf16* WT1[2] = {(bf16*)(ws + wofs),            (bf16*)(ws + wofs + wtsz)};
  bf16* WT2[2] = {(bf16*)(ws + wofs + 2 * wtsz), (bf16*)(ws + wofs + 3 * wtsz)};

  dim3 blk(256);
  dim3 gW((NWT + 255) / 256);
  dim3 gB((B + 63) / 64);
  dim3 gA((A + 63) / 64);
  dim3 gG((A * 75 + 255) / 256);

  for (int p = 0; p < 2; p++) {
    build_wt<<<gW, blk, 0, stream>>>(W_i[p], W_h[p], BFD, WT1[p]);
    build_wt<<<gW, blk, 0, stream>>>(W_o[p], W_o[p] + (size_t)AFD * HH, AFD, WT2[p]);
  }

  for (int p = 0; p < 2; p++) {
    float* out_p = (float*)d_out + (size_t)p * NMOLS * HH;
    // msg0 = relu(f_bonds @ W_i), row0=0
    gemm_p<0><<<gB, blk, 0, stream>>>(f_bonds[p], WT1[p], nullptr, nullptr,
                                      nullptr, nullptr, nullptr, msg0, nullptr, B);
    // iteration 1
    gather6_k<<<gG, blk, 0, stream>>>(msg0, a2b[p], amsg, A);
    gemm_p<1><<<gB, blk, 0, stream>>>(f_bonds[p], WT1[p], b2a[p], b2revb[p],
                                      amsg, msg0, nullptr, msg1, nullptr, B);
    // iteration 2
    gather6_k<<<gG, blk, 0, stream>>>(msg1, a2b[p], amsg, A);
    gemm_p<1><<<gB, blk, 0, stream>>>(f_bonds[p], WT1[p], b2a[p], b2revb[p],
                                      amsg, msg1, nullptr, msg0, nullptr, B);
    // final aggregation + output layer
    gather6_k<<<gG, blk, 0, stream>>>(msg0, a2b[p], amsg, A);
    gemm_p<2><<<gA, blk, 0, stream>>>(f_atoms[p], WT2[p], nullptr, nullptr,
                                      amsg, nullptr, b_o[p], nullptr, hid, A);
    // per-molecule mean readout
    readout_k<<<NMOLS, 320, 0, stream>>>(hid, mol_id[p], out_p, A);
  }
}